// Round 1
// baseline (451.425 us; speedup 1.0000x reference)
//
#include <hip/hip_runtime.h>

constexpr int kB = 32;
constexpr int kC = 512;
constexpr int kS = 56 * 56;   // 3136
constexpr int kP = 64;
constexpr float kEps = 1e-3f;

// ---------------------------------------------------------------------------
// K1: mask[b,s] = sum_c x[b,c,s] * wm[c]        (bm dropped: softmax-invariant)
// lane <-> s  => each c-iteration reads 64 consecutive floats (coalesced).
// ---------------------------------------------------------------------------
__global__ void k_mask(const float* __restrict__ x, const float* __restrict__ wm,
                       float* __restrict__ mask) {
    __shared__ float swm[kC];
    for (int c = threadIdx.x; c < kC; c += blockDim.x) swm[c] = wm[c];
    __syncthreads();

    const int b = blockIdx.y;
    const int s = blockIdx.x * blockDim.x + threadIdx.x;
    if (s >= kS) return;

    const float* xp = x + (size_t)b * kC * kS + s;
    float acc = 0.f;
#pragma unroll 8
    for (int c = 0; c < kC; ++c) acc += xp[(size_t)c * kS] * swm[c];
    mask[b * kS + s] = acc;
}

// ---------------------------------------------------------------------------
// K2: in-place softmax over S per batch. One block per b.
// ---------------------------------------------------------------------------
__global__ void k_softmax(float* __restrict__ mask) {
    const int b = blockIdx.x;
    float* m = mask + b * kS;
    const int tid  = threadIdx.x;
    const int lane = tid & 63;
    const int wave = tid >> 6;

    __shared__ float sred[4];
    __shared__ float sbc;

    // 1) max
    float mx = -INFINITY;
    for (int s = tid; s < kS; s += blockDim.x) mx = fmaxf(mx, m[s]);
    for (int off = 32; off; off >>= 1) mx = fmaxf(mx, __shfl_down(mx, off));
    if (lane == 0) sred[wave] = mx;
    __syncthreads();
    if (tid == 0) {
        float v = sred[0];
        for (int i = 1; i < 4; ++i) v = fmaxf(v, sred[i]);
        sbc = v;
    }
    __syncthreads();
    mx = sbc;

    // 2) exp + sum (store exp back)
    float sum = 0.f;
    for (int s = tid; s < kS; s += blockDim.x) {
        float e = expf(m[s] - mx);
        m[s] = e;
        sum += e;
    }
    for (int off = 32; off; off >>= 1) sum += __shfl_down(sum, off);
    if (lane == 0) sred[wave] = sum;
    __syncthreads();
    if (tid == 0) sbc = sred[0] + sred[1] + sred[2] + sred[3];
    __syncthreads();
    const float inv = 1.f / sbc;

    // 3) normalize
    for (int s = tid; s < kS; s += blockDim.x) m[s] *= inv;
}

// ---------------------------------------------------------------------------
// K3: context[b,c] = sum_s x[b,c,s] * attn[b,s].  One wave per (b,c) row,
// float4 loads (kS % 4 == 0), shuffle reduce.
// ---------------------------------------------------------------------------
__global__ void k_context(const float* __restrict__ x, const float* __restrict__ attn,
                          float* __restrict__ context) {
    const int gwave = (int)((blockIdx.x * blockDim.x + threadIdx.x) >> 6);
    const int lane  = threadIdx.x & 63;
    if (gwave >= kB * kC) return;
    const int b = gwave / kC;

    const float4* xr = (const float4*)(x + (size_t)gwave * kS);
    const float4* ar = (const float4*)(attn + (size_t)b * kS);

    float acc = 0.f;
    for (int i = lane; i < kS / 4; i += 64) {
        float4 xv = xr[i];
        float4 av = ar[i];
        acc += xv.x * av.x + xv.y * av.y + xv.z * av.z + xv.w * av.w;
    }
    for (int off = 32; off; off >>= 1) acc += __shfl_down(acc, off);
    if (lane == 0) context[gwave] = acc;
}

// ---------------------------------------------------------------------------
// K4: tiny MLP per batch: hid = relu(LN(w1@ctx + b1)); add = w2@hid + b2.
// One wave (64 threads) per b; p == lane.
// ---------------------------------------------------------------------------
__global__ void k_mlp(const float* __restrict__ context, const float* __restrict__ w1,
                      const float* __restrict__ b1, const float* __restrict__ ln_g,
                      const float* __restrict__ ln_b, const float* __restrict__ w2,
                      const float* __restrict__ b2, float* __restrict__ add) {
    const int b   = blockIdx.x;
    const int tid = threadIdx.x;   // 64 threads, tid == p

    __shared__ float ctx[kC];
    __shared__ float hid[kP];

    for (int c = tid; c < kC; c += 64) ctx[c] = context[b * kC + c];
    __syncthreads();

    // hid[p] = b1[p] + sum_c w1[p,c]*ctx[c]
    float h = b1[tid];
    const float* w1p = w1 + tid * kC;
    for (int c = 0; c < kC; ++c) h += w1p[c] * ctx[c];

    // LayerNorm over P (== wave width)
    float mu = h;
    for (int off = 32; off; off >>= 1) mu += __shfl_down(mu, off);
    mu = __shfl(mu, 0) * (1.f / kP);
    float d = h - mu;
    float var = d * d;
    for (int off = 32; off; off >>= 1) var += __shfl_down(var, off);
    var = __shfl(var, 0) * (1.f / kP);
    h = d * rsqrtf(var + kEps) * ln_g[tid] + ln_b[tid];
    h = fmaxf(h, 0.f);
    hid[tid] = h;
    __syncthreads();

    // add[c] = b2[c] + sum_p w2[c,p]*hid[p]
    for (int c = tid; c < kC; c += 64) {
        float a = b2[c];
        const float* w2c = w2 + c * kP;
#pragma unroll
        for (int p = 0; p < kP; ++p) a += w2c[p] * hid[p];
        add[b * kC + c] = a;
    }
}

// ---------------------------------------------------------------------------
// K5: out[b,c,s] = x[b,c,s] + gamma * add[b,c]   (float4 over flat index)
// ---------------------------------------------------------------------------
__global__ void k_out(const float* __restrict__ x, const float* __restrict__ add,
                      const float* __restrict__ gamma, float* __restrict__ out) {
    const size_t i4 = (size_t)blockIdx.x * blockDim.x + threadIdx.x;
    const size_t n4 = (size_t)kB * kC * kS / 4;
    if (i4 >= n4) return;
    const int bc = (int)(i4 / (kS / 4));
    const float a = gamma[0] * add[bc];
    float4 xv = ((const float4*)x)[i4];
    float4 o;
    o.x = xv.x + a; o.y = xv.y + a; o.z = xv.z + a; o.w = xv.w + a;
    ((float4*)out)[i4] = o;
}

extern "C" void kernel_launch(void* const* d_in, const int* in_sizes, int n_in,
                              void* d_out, int out_size, void* d_ws, size_t ws_size,
                              hipStream_t stream) {
    const float* x     = (const float*)d_in[0];
    const float* wm    = (const float*)d_in[1];
    // d_in[2] = bm: scalar shift before softmax -> mathematically a no-op, skipped
    const float* w1    = (const float*)d_in[3];
    const float* b1    = (const float*)d_in[4];
    const float* ln_g  = (const float*)d_in[5];
    const float* ln_b  = (const float*)d_in[6];
    const float* w2    = (const float*)d_in[7];
    const float* b2    = (const float*)d_in[8];
    const float* gamma = (const float*)d_in[9];
    float* out = (float*)d_out;

    float* ws      = (float*)d_ws;
    float* mask    = ws;                 // kB*kS floats (becomes attn in-place)
    float* context = mask + kB * kS;     // kB*kC floats
    float* add     = context + kB * kC;  // kB*kC floats

    k_mask<<<dim3((kS + 255) / 256, kB), 256, 0, stream>>>(x, wm, mask);
    k_softmax<<<kB, 256, 0, stream>>>(mask);
    k_context<<<(kB * kC) / 4, 256, 0, stream>>>(x, mask, context);
    k_mlp<<<kB, 64, 0, stream>>>(context, w1, b1, ln_g, ln_b, w2, b2, add);

    const size_t n4 = (size_t)kB * kC * kS / 4;
    k_out<<<(unsigned)((n4 + 255) / 256), 256, 0, stream>>>(x, add, gamma, out);
}

// Round 2
// 395.880 us; speedup vs baseline: 1.1403x; 1.1403x over previous
//
#include <hip/hip_runtime.h>

constexpr int kB = 32;
constexpr int kC = 512;
constexpr int kS = 56 * 56;   // 3136
constexpr int kP = 64;
constexpr float kEps = 1e-3f;

constexpr int kST = 32;          // spatial tile per block
constexpr int kNB = kS / kST;    // 98 tiles per batch
constexpr int kPadC = kC + 1;    // 513: LDS row pad (stride mod 32 == 1)

typedef float f4v __attribute__((ext_vector_type(4)));

// ---------------------------------------------------------------------------
// Pass A: one read of x does mask + local-softmax + unnormalized context.
// Block = (s-tile, b). LDS xs[s][c] transposed with +1 pad; all LDS access
// patterns are <=2-way bank aliasing (free on gfx950).
// Outputs per tile: pc[b][tile][c] = sum_s x[c,s]*exp(mask_s - M_loc)
//                   pmz[b][tile]   = (M_loc, sum_s exp(mask_s - M_loc))
// ---------------------------------------------------------------------------
__global__ __launch_bounds__(512)
void k_fused_pass(const float* __restrict__ x, const float* __restrict__ wm,
                  float* __restrict__ pc, float* __restrict__ pmz) {
    __shared__ float xs[kST][kPadC];   // 32*513*4 = 65.7 KB -> 2 blocks/CU
    __shared__ float swm[kC];
    __shared__ float pm[16][kST];      // mask partials: 16 c-chunks x 32 s
    __shared__ float es[kST];          // exp(mask - M_loc)

    const int b    = blockIdx.y;
    const int tile = blockIdx.x;
    const int s0   = tile * kST;
    const int t    = threadIdx.x;

    for (int c = t; c < kC; c += 512) swm[c] = wm[c];

    // ---- stage x[b, :, s0:s0+32] into LDS, transposed to [s][c] ----
    const float* xb = x + (size_t)b * kC * kS + s0;
    {
        const int c0 = t >> 3;         // 0..63
        const int si = t & 7;          // float4 index within the 32-s tile
        for (int cc = 0; cc < kC; cc += 64) {
            const int c = cc + c0;
            f4v v = *(const f4v*)(xb + (size_t)c * kS + si * 4);
            xs[si * 4 + 0][c] = v.x;
            xs[si * 4 + 1][c] = v.y;
            xs[si * 4 + 2][c] = v.z;
            xs[si * 4 + 3][c] = v.w;
        }
    }
    __syncthreads();

    // ---- mask[s] = sum_c xs[s][c]*wm[c]; split c over 16 chunks ----
    {
        const int s  = t & 31;
        const int ch = t >> 5;         // 0..15
        const int cb = ch * 32;
        float acc = 0.f;
#pragma unroll 8
        for (int i = 0; i < 32; ++i) acc += xs[s][cb + i] * swm[cb + i];
        pm[ch][s] = acc;
    }
    __syncthreads();

    // ---- wave 0: reduce mask, local softmax stats ----
    if (t < 64) {
        float v = 0.f, m = -INFINITY;
        if (t < kST) {
#pragma unroll
            for (int ch = 0; ch < 16; ++ch) v += pm[ch][t];
            m = v;
        }
        float mx = m;
        for (int off = 32; off; off >>= 1) mx = fmaxf(mx, __shfl_xor(mx, off));
        const float e = (t < kST) ? expf(v - mx) : 0.f;
        float sum = e;
        for (int off = 32; off; off >>= 1) sum += __shfl_xor(sum, off);
        if (t < kST) es[t] = e;
        if (t == 0) {
            pmz[(b * kNB + tile) * 2 + 0] = mx;
            pmz[(b * kNB + tile) * 2 + 1] = sum;
        }
    }
    __syncthreads();

    // ---- context partial: thread per c (t == c), conflict-free column read ----
    {
        float acc = 0.f;
#pragma unroll 8
        for (int s = 0; s < kST; ++s) acc += xs[s][t] * es[s];
        pc[((size_t)b * kNB + tile) * kC + t] = acc;
    }
}

// ---------------------------------------------------------------------------
// Pass B: per batch — combine 98 tile-partials with global softmax rescale,
// then the tiny MLP (w1 -> LN -> ReLU -> w2). One block per b, 512 threads.
// ---------------------------------------------------------------------------
__global__ __launch_bounds__(512)
void k_combine_mlp(const float* __restrict__ pc, const float* __restrict__ pmz,
                   const float* __restrict__ w1, const float* __restrict__ b1,
                   const float* __restrict__ ln_g, const float* __restrict__ ln_b,
                   const float* __restrict__ w2, const float* __restrict__ b2,
                   float* __restrict__ add) {
    const int b = blockIdx.x;
    const int t = threadIdx.x;
    __shared__ float scale[kNB];     // exp(M_i - M)/Z
    __shared__ float ctx[kC];
    __shared__ float hp[kP][9];      // hid partials (pad 9: bank-spread)
    __shared__ float hid[kP];

    // wave 0: global max + Z over 98 tiles
    if (t < 64) {
        const float m1 = (t      < kNB) ? pmz[(b * kNB + t     ) * 2] : -INFINITY;
        const float m2 = (t + 64 < kNB) ? pmz[(b * kNB + t + 64) * 2] : -INFINITY;
        float m = fmaxf(m1, m2);
        for (int off = 32; off; off >>= 1) m = fmaxf(m, __shfl_xor(m, off));
        const float e1 = (t      < kNB) ? expf(m1 - m) : 0.f;
        const float e2 = (t + 64 < kNB) ? expf(m2 - m) : 0.f;
        float z = 0.f;
        if (t      < kNB) z += pmz[(b * kNB + t     ) * 2 + 1] * e1;
        if (t + 64 < kNB) z += pmz[(b * kNB + t + 64) * 2 + 1] * e2;
        for (int off = 32; off; off >>= 1) z += __shfl_xor(z, off);
        const float inv = 1.f / z;
        if (t      < kNB) scale[t]      = e1 * inv;
        if (t + 64 < kNB) scale[t + 64] = e2 * inv;
    }
    __syncthreads();

    // ctx[c] = sum_i pc[i][c] * scale[i]   (coalesced over c)
    {
        float acc = 0.f;
        for (int i = 0; i < kNB; ++i)
            acc += pc[((size_t)b * kNB + i) * kC + t] * scale[i];
        ctx[t] = acc;
    }
    __syncthreads();

    // hid partials: p = t&63, chunk k = t>>6 sums 64 c's (ctx read = broadcast)
    {
        const int p = t & 63, k = t >> 6;
        const float* w1p = w1 + p * kC + k * 64;
        const float* cxp = ctx + k * 64;
        float acc = 0.f;
#pragma unroll 8
        for (int i = 0; i < 64; ++i) acc += w1p[i] * cxp[i];
        hp[p][k] = acc;
    }
    __syncthreads();

    if (t < 64) {
        float h = b1[t];
#pragma unroll
        for (int k = 0; k < 8; ++k) h += hp[t][k];
        // LayerNorm over P=64 (one wave)
        float mu = h;
        for (int off = 32; off; off >>= 1) mu += __shfl_xor(mu, off);
        mu *= (1.f / kP);
        const float d = h - mu;
        float var = d * d;
        for (int off = 32; off; off >>= 1) var += __shfl_xor(var, off);
        var *= (1.f / kP);
        const float hv = d * rsqrtf(var + kEps) * ln_g[t] + ln_b[t];
        hid[t] = fmaxf(hv, 0.f);
    }
    __syncthreads();

    // add[c] = b2[c] + w2[c,:]·hid
    {
        float a = b2[t];
        const float* w2c = w2 + t * kP;
#pragma unroll
        for (int p = 0; p < kP; ++p) a += w2c[p] * hid[p];
        add[b * kC + t] = a;
    }
}

// ---------------------------------------------------------------------------
// Pass C: out = x + gamma*add, float4, nontemporal stores (keep x in L3).
// ---------------------------------------------------------------------------
__global__ __launch_bounds__(256)
void k_out(const float* __restrict__ x, const float* __restrict__ add,
           const float* __restrict__ gamma, float* __restrict__ out) {
    const size_t i4 = (size_t)blockIdx.x * blockDim.x + threadIdx.x;
    const size_t n4 = (size_t)kB * kC * kS / 4;
    if (i4 >= n4) return;
    const int bc = (int)(i4 / (kS / 4));
    const float a = gamma[0] * add[bc];
    f4v xv = ((const f4v*)x)[i4];
    f4v o = {xv.x + a, xv.y + a, xv.z + a, xv.w + a};
    __builtin_nontemporal_store(o, (f4v*)out + i4);
}

extern "C" void kernel_launch(void* const* d_in, const int* in_sizes, int n_in,
                              void* d_out, int out_size, void* d_ws, size_t ws_size,
                              hipStream_t stream) {
    const float* x     = (const float*)d_in[0];
    const float* wm    = (const float*)d_in[1];
    // d_in[2] = bm: uniform pre-softmax shift -> no-op, skipped
    const float* w1    = (const float*)d_in[3];
    const float* b1    = (const float*)d_in[4];
    const float* ln_g  = (const float*)d_in[5];
    const float* ln_b  = (const float*)d_in[6];
    const float* w2    = (const float*)d_in[7];
    const float* b2    = (const float*)d_in[8];
    const float* gamma = (const float*)d_in[9];
    float* out = (float*)d_out;

    float* ws  = (float*)d_ws;
    float* pc  = ws;                               // kB*kNB*kC floats (6.4 MB)
    float* pmz = pc + (size_t)kB * kNB * kC;       // kB*kNB*2 floats
    float* add = pmz + (size_t)kB * kNB * 2;       // kB*kC floats

    k_fused_pass<<<dim3(kNB, kB), 512, 0, stream>>>(x, wm, pc, pmz);
    k_combine_mlp<<<kB, 512, 0, stream>>>(pc, pmz, w1, b1, ln_g, ln_b, w2, b2, add);

    const size_t n4 = (size_t)kB * kC * kS / 4;
    k_out<<<(unsigned)((n4 + 255) / 256), 256, 0, stream>>>(x, add, gamma, out);
}